// Round 17
// baseline (4833.925 us; speedup 1.0000x reference)
//
#include <hip/hip_runtime.h>
#include <hip/hip_bf16.h>
#include <cstddef>
#include <cstdint>

namespace {

constexpr int B = 64, CIN = 3, IMG = 224, PS = 16, GRID_ = 14, NPATCH = 196;
constexpr int D = 768, H = 12, HD = 64, FFD = 3072, NC = 1000;
constexpr int S1 = 197, S2 = 99, KEEP = 98, PRUNE = 6, LAYERS = 12;
constexpr float LN_EPS = 1e-6f;

typedef __attribute__((ext_vector_type(8))) short bf16x8;
typedef __attribute__((ext_vector_type(4))) float f32x4;

__device__ inline float wave_red_sum(float v) {
  #pragma unroll
  for (int off = 32; off > 0; off >>= 1) v += __shfl_xor(v, off, 64);
  return v;
}

// async global->LDS DMA, 16B per lane; LDS dest is wave-uniform base + lane*16
__device__ inline void gl16(const __hip_bfloat16* g, __hip_bfloat16* l) {
  __builtin_amdgcn_global_load_lds(
      (const __attribute__((address_space(1))) void*)g,
      (__attribute__((address_space(3))) void*)l,
      16, 0, 0);
}

// ---------------- weight transpose-convert: src f32 [R][C] -> dst bf16 [C][R] ----------------
__global__ __launch_bounds__(256) void tcvt_k(const float* __restrict__ src,
                                              __hip_bfloat16* __restrict__ dst,
                                              int R, int C, size_t lstride) {
  src += (size_t)blockIdx.z * lstride;
  dst += (size_t)blockIdx.z * lstride;
  __shared__ float tile[32][33];
  int c0 = blockIdx.x * 32, r0 = blockIdx.y * 32;
  int tx = threadIdx.x & 31, ty = threadIdx.x >> 5;  // ty 0..7
  #pragma unroll
  for (int i = 0; i < 32; i += 8) {
    int r = r0 + ty + i, c = c0 + tx;
    tile[ty + i][tx] = (r < R && c < C) ? src[(size_t)r * C + c] : 0.f;
  }
  __syncthreads();
  #pragma unroll
  for (int i = 0; i < 32; i += 8) {
    int c = c0 + ty + i, r = r0 + tx;
    if (c < C && r < R) dst[(size_t)c * R + r] = __float2bfloat16(tile[tx][ty + i]);
  }
}

// ---------------- patch extraction -> bf16 patches (B*196, 768), 8 elems/thread ----------------
__global__ void patchify_k(const float* __restrict__ x, __hip_bfloat16* __restrict__ out) {
  size_t idx8 = (size_t)blockIdx.x * blockDim.x + threadIdx.x;
  size_t total8 = (size_t)B * NPATCH * D / 8;
  if (idx8 >= total8) return;
  size_t idx = idx8 * 8;
  int row = (int)(idx / D), k = (int)(idx % D);  // k multiple of 8
  int b = row / NPATCH, n = row % NPATCH;
  int gr = n / GRID_, gc = n % GRID_;
  int c = k >> 8, rr = (k & 255) >> 4, cc = k & 15;  // cc in {0,8}
  const float* src = &x[((size_t)(b * CIN + c) * IMG + (gr * PS + rr)) * IMG + gc * PS + cc];
  float4 v0 = *(const float4*)src;
  float4 v1 = *(const float4*)(src + 4);
  __hip_bfloat16 tmp[8] = {
      __float2bfloat16(v0.x), __float2bfloat16(v0.y), __float2bfloat16(v0.z), __float2bfloat16(v0.w),
      __float2bfloat16(v1.x), __float2bfloat16(v1.y), __float2bfloat16(v1.z), __float2bfloat16(v1.w)};
  *(bf16x8*)&out[idx] = *(bf16x8*)tmp;
}

// ---------------- bf16 MFMA GEMM: BMx128, BK=32, 3-deep counted-vmcnt (R13 structure) ----------------
// BM=128 (LOADS=4/stage, vmcnt 8/4/0) or BM=64 (LOADS=3/stage, vmcnt 6/3/0).
// Compile-time K (KC) + hoisted per-lane global base pointers.
// XOR swizzle: LDS slot(row,chunk)=chunk^((row>>1)&3), both-sides involution.
// MODE 0: bf16 out = acc + bias        (qkv)
// MODE 1: f32 patch-embed scatter      (patch embed)
// MODE 2: f32 out += acc + bias        (residual: proj, fc2)
// MODE 3: bf16 out = gelu(acc + bias)  (fc1)
template <int MODE, int KC, int BM>
__global__ __launch_bounds__(256) void bgemm_k(
    const __hip_bfloat16* __restrict__ A, const __hip_bfloat16* __restrict__ BT,
    const float* __restrict__ bias, void* __restrict__ Cc,
    int M, int N, const float* __restrict__ extra) {
  constexpr int MR = BM / 32;          // per-wave M fragments (4 or 2)
  __shared__ __hip_bfloat16 As[3][BM * 32];
  __shared__ __hip_bfloat16 Bs[3][128 * 32];
  int tid = threadIdx.x, lane = tid & 63, wv = tid >> 6;
  int wr = wv >> 1, wc = wv & 1;
  int m0 = blockIdx.y * BM, n0 = blockIdx.x * 128;
  int fr = lane & 15, fq = lane >> 4;
  int srow = lane >> 2;
  int scd = (lane & 3) ^ ((lane >> 3) & 3);
  int rswz = (fq ^ ((fr >> 1) & 3)) * 8;
  constexpr int NK = KC >> 5;

  // hoisted per-lane global bases (clamp + 64-bit mul once)
  int ar0 = m0 + (BM == 128 ? wv * 32 : wv * 16) + srow;
  int ga0 = (ar0 < M) ? ar0 : (M - 1);
  const __hip_bfloat16* pa0 = A + (size_t)ga0 * KC + scd * 8;
  const __hip_bfloat16* pa1 = pa0;
  if constexpr (BM == 128) {
    int ar1 = ar0 + 16;
    int ga1 = (ar1 < M) ? ar1 : (M - 1);
    pa1 = A + (size_t)ga1 * KC + scd * 8;
  }
  int br0 = n0 + wv * 32 + srow, br1 = br0 + 16;
  int gb0 = (br0 < N) ? br0 : (N - 1), gb1 = (br1 < N) ? br1 : (N - 1);
  const __hip_bfloat16* pb0 = BT + (size_t)gb0 * KC + scd * 8;
  const __hip_bfloat16* pb1 = BT + (size_t)gb1 * KC + scd * 8;

  auto stage = [&](int buf, int kt) {
    int ko = kt << 5;
    if constexpr (BM == 128) {
      gl16(pa0 + ko, &As[buf][(wv * 32) * 32]);
      gl16(pa1 + ko, &As[buf][(wv * 32 + 16) * 32]);
    } else {
      gl16(pa0 + ko, &As[buf][(wv * 16) * 32]);
    }
    gl16(pb0 + ko, &Bs[buf][(wv * 32) * 32]);
    gl16(pb1 + ko, &Bs[buf][(wv * 32 + 16) * 32]);
  };

  f32x4 acc[MR][4] = {};
  stage(0, 0);
  stage(1, 1);                       // NK >= 2 always
  for (int kt = 0; kt < NK; ++kt) {
    int buf = kt % 3;
    if (kt + 2 < NK) {
      stage((kt + 2) % 3, kt + 2);
      if constexpr (BM == 128) asm volatile("s_waitcnt vmcnt(8)" ::: "memory");
      else                     asm volatile("s_waitcnt vmcnt(6)" ::: "memory");
    } else if (kt + 1 < NK) {
      if constexpr (BM == 128) asm volatile("s_waitcnt vmcnt(4)" ::: "memory");
      else                     asm volatile("s_waitcnt vmcnt(3)" ::: "memory");
    } else {
      asm volatile("s_waitcnt vmcnt(0)" ::: "memory");
    }
    asm volatile("s_barrier" ::: "memory");  // all waves' tile-kt DMA visible
    bf16x8 af[MR], bg[4];
    #pragma unroll
    for (int m = 0; m < MR; ++m)
      af[m] = *(const bf16x8*)&As[buf][(wr * (BM / 2) + m * 16 + fr) * 32 + rswz];
    #pragma unroll
    for (int n = 0; n < 4; ++n)
      bg[n] = *(const bf16x8*)&Bs[buf][(wc * 64 + n * 16 + fr) * 32 + rswz];
    #pragma unroll
    for (int m = 0; m < MR; ++m)
      #pragma unroll
      for (int n = 0; n < 4; ++n)
        acc[m][n] = __builtin_amdgcn_mfma_f32_16x16x32_bf16(af[m], bg[n], acc[m][n], 0, 0, 0);
    asm volatile("s_waitcnt lgkmcnt(0)" ::: "memory");  // my LDS reads complete
    asm volatile("s_barrier" ::: "memory");  // all waves done reading buf kt
  }
  #pragma unroll
  for (int m = 0; m < MR; ++m) {
    #pragma unroll
    for (int n = 0; n < 4; ++n) {
      #pragma unroll
      for (int j = 0; j < 4; ++j) {
        int row = m0 + wr * (BM / 2) + m * 16 + fq * 4 + j;
        int col = n0 + wc * 64 + n * 16 + fr;
        if (row >= M || col >= N) continue;
        float v = acc[m][n][j] + bias[col];
        if (MODE == 0) {
          ((__hip_bfloat16*)Cc)[(size_t)row * N + col] = __float2bfloat16(v);
        } else if (MODE == 1) {
          int b = row / NPATCH, nn = row % NPATCH;
          ((float*)Cc)[((size_t)(b * S1 + 1 + nn)) * D + col] = v + extra[(size_t)(1 + nn) * D + col];
        } else if (MODE == 2) {
          ((float*)Cc)[(size_t)row * N + col] += v;
        } else {
          float g = 0.5f * v * (1.0f + erff(v * 0.7071067811865476f));
          ((__hip_bfloat16*)Cc)[(size_t)row * N + col] = __float2bfloat16(g);
        }
      }
    }
  }
}

// ---------------- f32 GEMM (head only): C = A @ B + bias ----------------
__global__ __launch_bounds__(256) void gemm_k(
    const float* __restrict__ A, const float* __restrict__ Bw,
    const float* __restrict__ bias, float* __restrict__ Cc,
    int M, int N, int K) {
  __shared__ float As[64][17];
  __shared__ float Bs[16][64];
  int tid = threadIdx.x;
  int tx = tid & 15, ty = tid >> 4;
  int m0 = blockIdx.y * 64, n0 = blockIdx.x * 64;
  float acc[4][4] = {};
  for (int k0 = 0; k0 < K; k0 += 16) {
    #pragma unroll
    for (int j = 0; j < 4; ++j) {
      int i = tid + 256 * j;
      int r = i >> 4, c = i & 15;
      int gr = m0 + r;
      As[r][c] = (gr < M) ? A[(size_t)gr * K + (k0 + c)] : 0.f;
    }
    #pragma unroll
    for (int j = 0; j < 4; ++j) {
      int i = tid + 256 * j;
      int r = i >> 6, c = i & 63;
      int gc = n0 + c;
      Bs[r][c] = (gc < N) ? Bw[(size_t)(k0 + r) * N + gc] : 0.f;
    }
    __syncthreads();
    #pragma unroll
    for (int kk = 0; kk < 16; ++kk) {
      float a[4], bb[4];
      #pragma unroll
      for (int ii = 0; ii < 4; ++ii) a[ii] = As[ty * 4 + ii][kk];
      #pragma unroll
      for (int jj = 0; jj < 4; ++jj) bb[jj] = Bs[kk][tx * 4 + jj];
      #pragma unroll
      for (int ii = 0; ii < 4; ++ii)
        #pragma unroll
        for (int jj = 0; jj < 4; ++jj) acc[ii][jj] = fmaf(a[ii], bb[jj], acc[ii][jj]);
    }
    __syncthreads();
  }
  #pragma unroll
  for (int ii = 0; ii < 4; ++ii) {
    int row = m0 + ty * 4 + ii;
    if (row >= M) continue;
    #pragma unroll
    for (int jj = 0; jj < 4; ++jj) {
      int col = n0 + tx * 4 + jj;
      if (col >= N) continue;
      Cc[(size_t)row * N + col] = acc[ii][jj] + bias[col];
    }
  }
}

// ---------------- cls token init ----------------
__global__ void cls_init_k(float* __restrict__ t, const float* __restrict__ cls,
                           const float* __restrict__ pos) {
  int idx = blockIdx.x * blockDim.x + threadIdx.x;
  if (idx >= B * D) return;
  int b = idx / D, d = idx % D;
  t[(size_t)b * S1 * D + d] = cls[d] + pos[d];
}

// ---------------- LayerNorm over last dim (768): 192 threads, float4 loads ----------------
template <typename OutT>
__global__ __launch_bounds__(192) void ln_k(const float* __restrict__ in, OutT* __restrict__ out,
                                            const float* __restrict__ g, const float* __restrict__ bta,
                                            size_t istride, size_t ostride) {
  int row = blockIdx.x, tid = threadIdx.x;  // 192 * 4 = 768
  const float4* p = (const float4*)(in + (size_t)row * istride);
  float4 v = p[tid];
  float s = v.x + v.y + v.z + v.w;
  float s2 = v.x * v.x + v.y * v.y + v.z * v.z + v.w * v.w;
  s = wave_red_sum(s);
  s2 = wave_red_sum(s2);
  __shared__ float r1[3], r2[3];
  int lane = tid & 63, w = tid >> 6;
  if (lane == 0) { r1[w] = s; r2[w] = s2; }
  __syncthreads();
  s = r1[0] + r1[1] + r1[2];
  s2 = r2[0] + r2[1] + r2[2];
  float mean = s * (1.0f / 768.0f);
  float var = s2 * (1.0f / 768.0f) - mean * mean;
  float rs = rsqrtf(var + LN_EPS);
  float4 gv = ((const float4*)g)[tid];
  float4 bv = ((const float4*)bta)[tid];
  float o0 = (v.x - mean) * rs * gv.x + bv.x;
  float o1 = (v.y - mean) * rs * gv.y + bv.y;
  float o2 = (v.z - mean) * rs * gv.z + bv.z;
  float o3 = (v.w - mean) * rs * gv.w + bv.w;
  if constexpr (sizeof(OutT) == 2) {
    __hip_bfloat16 hb[4] = {__float2bfloat16(o0), __float2bfloat16(o1),
                            __float2bfloat16(o2), __float2bfloat16(o3)};
    *(uint2*)((__hip_bfloat16*)out + (size_t)row * ostride + tid * 4) = *(uint2*)hb;
  } else {
    ((float4*)((float*)out + (size_t)row * ostride))[tid] = make_float4(o0, o1, o2, o3);
  }
}

// ---------------- MFMA attention: one block (4 waves) per (b,h) ----------------
// PV phase: P-fragments (ap) hoisted out of the dt loop (they depend only on kc)
// -> removes 3x redundant ds_read_b128 of the P tile per q-tile.
template <int NT16>
__global__ __launch_bounds__(256) void attn3_k(const __hip_bfloat16* __restrict__ qkv,
                                               __hip_bfloat16* __restrict__ o, int S) {
  constexpr int NT32 = (NT16 + 1) / 2;
  constexpr int COLS = NT32 * 32;
  constexpr int STR = COLS + 8;
  __shared__ __hip_bfloat16 VT[64 * STR];      // VT[d][key]
  __shared__ __hip_bfloat16 P[4][16 * STR];    // per-wave P tile [q][key]
  int bh = blockIdx.x;
  int b = bh / H, hh = bh % H;
  int tid = threadIdx.x, lane = tid & 63, wv = tid >> 6;
  int fr = lane & 15, fq = lane >> 4;
  const size_t rs = 3 * D;
  const __hip_bfloat16* qb = qkv + ((size_t)b * S) * rs + hh * HD;
  const __hip_bfloat16* kb = qb + D;
  const __hip_bfloat16* vb = qb + 2 * D;
  // vectorized V staging: one bf16x8 global load per (key, 8-d chunk)
  for (int idx = tid; idx < COLS * 8; idx += 256) {
    int key = idx >> 3, d0 = (idx & 7) * 8;
    bf16x8 v = {};
    if (key < S) v = *(const bf16x8*)(vb + (size_t)key * rs + d0);
    #pragma unroll
    for (int j = 0; j < 8; ++j)
      VT[(d0 + j) * STR + key] = ((const __hip_bfloat16*)&v)[j];
  }
  if (NT16 & 1) {
    const __hip_bfloat16 z = __float2bfloat16(0.f);
    for (int idx = lane; idx < 16 * 16; idx += 64)
      P[wv][(idx >> 4) * STR + NT16 * 16 + (idx & 15)] = z;
  }
  __syncthreads();

  for (int qt = wv; qt * 16 < S; qt += 4) {
    int q0 = qt * 16;
    int qrow = q0 + fr;
    const __hip_bfloat16* qp = qb + (size_t)(qrow < S ? qrow : 0) * rs + fq * 8;
    bf16x8 aq0 = *(const bf16x8*)(qp);
    bf16x8 aq1 = *(const bf16x8*)(qp + 32);
    f32x4 sc[NT16];
    #pragma unroll
    for (int kt = 0; kt < NT16; ++kt) {
      int krow = kt * 16 + fr;
      const __hip_bfloat16* kp = kb + (size_t)(krow < S ? krow : 0) * rs + fq * 8;
      bf16x8 bk0 = *(const bf16x8*)(kp);
      bf16x8 bk1 = *(const bf16x8*)(kp + 32);
      f32x4 a = {};
      a = __builtin_amdgcn_mfma_f32_16x16x32_bf16(aq0, bk0, a, 0, 0, 0);
      a = __builtin_amdgcn_mfma_f32_16x16x32_bf16(aq1, bk1, a, 0, 0, 0);
      sc[kt] = a;
    }
    float lj[4];
    #pragma unroll
    for (int jj = 0; jj < 4; ++jj) {
      float mx = -1e30f;
      #pragma unroll
      for (int kt = 0; kt < NT16; ++kt) {
        float v = sc[kt][jj] * 0.125f;
        if (kt * 16 + fr >= S) v = -1e30f;
        sc[kt][jj] = v;
        mx = fmaxf(mx, v);
      }
      mx = fmaxf(mx, __shfl_xor(mx, 1, 64));
      mx = fmaxf(mx, __shfl_xor(mx, 2, 64));
      mx = fmaxf(mx, __shfl_xor(mx, 4, 64));
      mx = fmaxf(mx, __shfl_xor(mx, 8, 64));
      float sum = 0.f;
      #pragma unroll
      for (int kt = 0; kt < NT16; ++kt) {
        float p = __expf(sc[kt][jj] - mx);
        sc[kt][jj] = p;
        sum += p;
      }
      sum += __shfl_xor(sum, 1, 64);
      sum += __shfl_xor(sum, 2, 64);
      sum += __shfl_xor(sum, 4, 64);
      sum += __shfl_xor(sum, 8, 64);
      lj[jj] = 1.0f / sum;
    }
    __hip_bfloat16* pw = &P[wv][0];
    #pragma unroll
    for (int kt = 0; kt < NT16; ++kt)
      #pragma unroll
      for (int jj = 0; jj < 4; ++jj)
        pw[(fq * 4 + jj) * STR + kt * 16 + fr] = __float2bfloat16(sc[kt][jj]);
    // hoisted P fragments: depend only on kc, not dt
    bf16x8 ap[NT32];
    #pragma unroll
    for (int kc = 0; kc < NT32; ++kc)
      ap[kc] = *(const bf16x8*)&pw[fr * STR + kc * 32 + fq * 8];
    #pragma unroll
    for (int dt = 0; dt < 4; ++dt) {
      f32x4 oa = {};
      #pragma unroll
      for (int kc = 0; kc < NT32; ++kc) {
        bf16x8 bv = *(const bf16x8*)&VT[(dt * 16 + fr) * STR + kc * 32 + fq * 8];
        oa = __builtin_amdgcn_mfma_f32_16x16x32_bf16(ap[kc], bv, oa, 0, 0, 0);
      }
      #pragma unroll
      for (int jj = 0; jj < 4; ++jj) {
        int orow = q0 + fq * 4 + jj;
        if (orow < S)
          o[((size_t)(b * S + orow)) * D + hh * HD + dt * 16 + fr] =
              __float2bfloat16(oa[jj] * lj[jj]);
      }
    }
  }
}

// ---------------- token scores: float4 loads ----------------
__global__ void score_k(const float* __restrict__ t, float* __restrict__ scores) {
  int gw = (blockIdx.x * blockDim.x + threadIdx.x) >> 6;
  int lane = threadIdx.x & 63;
  if (gw >= B * NPATCH) return;
  int b = gw / NPATCH, n = gw % NPATCH;
  const float4* p = (const float4*)(t + ((size_t)(b * S1) + 1 + n) * D);
  float a = 0.f;
  #pragma unroll
  for (int j = lane; j < D / 4; j += 64) {
    float4 v = p[j];
    a += v.x * v.x + v.y * v.y + v.z * v.z + v.w * v.w;
  }
  a = wave_red_sum(a);
  if (lane == 0) scores[gw] = sqrtf(a);
}

// ---------------- top-98 selection (exact jax.lax.top_k tie-break) ----------------
__global__ __launch_bounds__(256) void select_k(const float* __restrict__ scores, int* __restrict__ map) {
  int b = blockIdx.x;
  __shared__ float s[NPATCH];
  __shared__ int flag[NPATCH];
  int i = threadIdx.x;
  if (i < NPATCH) s[i] = scores[b * NPATCH + i];
  __syncthreads();
  if (i < NPATCH) {
    float si = s[i];
    int r = 0;
    for (int j = 0; j < NPATCH; ++j) {
      float sj = s[j];
      r += (sj > si) || (sj == si && j < i);
    }
    flag[i] = (r < KEEP) ? 1 : 0;
  }
  __syncthreads();
  if (i < NPATCH && flag[i]) {
    int p = 0;
    for (int j = 0; j < i; ++j) p += flag[j];
    map[b * (KEEP + 1) + 1 + p] = 1 + i;
  }
  if (i == 0) map[b * (KEEP + 1)] = 0;
}

// ---------------- gather selected rows: float4 copies ----------------
__global__ void gather_k(const float* __restrict__ t, const int* __restrict__ map,
                         float* __restrict__ t2) {
  int br = blockIdx.x;
  int b = br / S2;
  int src = map[br];
  const float4* p = (const float4*)(t + ((size_t)b * S1 + src) * D);
  float4* q = (float4*)(t2 + (size_t)br * D);
  for (int j = threadIdx.x; j < D / 4; j += blockDim.x) q[j] = p[j];
}

}  // namespace

extern "C" void kernel_launch(void* const* d_in, const int* in_sizes, int n_in,
                              void* d_out, int out_size, void* d_ws, size_t ws_size,
                              hipStream_t stream) {
  const float* x       = (const float*)d_in[0];
  const float* patch_w = (const float*)d_in[1];
  const float* patch_b = (const float*)d_in[2];
  const float* cls_tok = (const float*)d_in[3];
  const float* pos_emb = (const float*)d_in[4];
  const float* ln1_g   = (const float*)d_in[5];
  const float* ln1_b   = (const float*)d_in[6];
  const float* qkv_w   = (const float*)d_in[7];
  const float* qkv_b   = (const float*)d_in[8];
  const float* proj_w  = (const float*)d_in[9];
  const float* proj_b  = (const float*)d_in[10];
  const float* ln2_g   = (const float*)d_in[11];
  const float* ln2_b   = (const float*)d_in[12];
  const float* fc1_w   = (const float*)d_in[13];
  const float* fc1_b   = (const float*)d_in[14];
  const float* fc2_w   = (const float*)d_in[15];
  const float* fc2_b   = (const float*)d_in[16];
  const float* norm_g  = (const float*)d_in[17];
  const float* norm_b  = (const float*)d_in[18];
  const float* head_w  = (const float*)d_in[19];
  const float* head_b  = (const float*)d_in[20];
  float* out = (float*)d_out;

  // ---- workspace layout (256B-aligned regions) ----
  char* wp = (char*)d_ws;
  auto alloc = [&](size_t bytes) { char* r = wp; wp += (bytes + 255) & ~(size_t)255; return r; };
  float* t   = (float*)alloc((size_t)B * S1 * D * 4);
  float* t2  = (float*)alloc((size_t)B * S2 * D * 4);
  float* hf  = (float*)alloc((size_t)B * D * 4);
  float* scores = (float*)alloc((size_t)B * NPATCH * 4);
  int*   map    = (int*)alloc((size_t)B * S2 * 4);
  __hip_bfloat16* h   = (__hip_bfloat16*)alloc((size_t)B * S1 * D * 2);
  __hip_bfloat16* qkv = (__hip_bfloat16*)alloc((size_t)B * S1 * 3 * D * 2);
  __hip_bfloat16* ff  = (__hip_bfloat16*)alloc((size_t)B * S1 * FFD * 2);
  __hip_bfloat16* qkvT  = (__hip_bfloat16*)alloc((size_t)LAYERS * 3 * D * D * 2);
  __hip_bfloat16* projT = (__hip_bfloat16*)alloc((size_t)LAYERS * D * D * 2);
  __hip_bfloat16* fc1T  = (__hip_bfloat16*)alloc((size_t)LAYERS * FFD * D * 2);
  __hip_bfloat16* fc2T  = (__hip_bfloat16*)alloc((size_t)LAYERS * D * FFD * 2);
  __hip_bfloat16* patchT = (__hip_bfloat16*)alloc((size_t)D * D * 2);
  __hip_bfloat16* patches = ff;  // alias: ff unused during patch embed

  // ---- weight transpose-convert ----
  { dim3 g(3 * D / 32, D / 32, LAYERS);
    tcvt_k<<<g, 256, 0, stream>>>(qkv_w, qkvT, D, 3 * D, (size_t)D * 3 * D); }
  { dim3 g(D / 32, D / 32, LAYERS);
    tcvt_k<<<g, 256, 0, stream>>>(proj_w, projT, D, D, (size_t)D * D); }
  { dim3 g(FFD / 32, D / 32, LAYERS);
    tcvt_k<<<g, 256, 0, stream>>>(fc1_w, fc1T, D, FFD, (size_t)D * FFD); }
  { dim3 g(D / 32, FFD / 32, LAYERS);
    tcvt_k<<<g, 256, 0, stream>>>(fc2_w, fc2T, FFD, D, (size_t)FFD * D); }
  { dim3 g(D / 32, D / 32, 1);
    tcvt_k<<<g, 256, 0, stream>>>(patch_w, patchT, D, D, 0); }

  // ---- patch embedding (+cls, +pos) ----
  {
    size_t total8 = (size_t)B * NPATCH * D / 8;
    patchify_k<<<(unsigned)((total8 + 255) / 256), 256, 0, stream>>>(x, patches);
    dim3 g(D / 128, (B * NPATCH) / 128);
    bgemm_k<1, 768, 128><<<g, 256, 0, stream>>>(patches, patchT, patch_b, t, B * NPATCH, D, pos_emb);
    cls_init_k<<<(B * D + 255) / 256, 256, 0, stream>>>(t, cls_tok, pos_emb);
  }

  auto run_block = [&](float* tb, int S, int l) {
    int M = B * S;
    int mb128 = (M + 127) / 128;
    int mb64 = (M + 63) / 64;
    ln_k<__hip_bfloat16><<<M, 192, 0, stream>>>(tb, h, ln1_g + (size_t)l * D, ln1_b + (size_t)l * D, D, D);
    { dim3 g(3 * D / 128, mb128);
      bgemm_k<0, 768, 128><<<g, 256, 0, stream>>>(h, qkvT + (size_t)l * 3 * D * D, qkv_b + (size_t)l * 3 * D,
                                                  qkv, M, 3 * D, nullptr); }
    if (S == S1) attn3_k<13><<<B * H, 256, 0, stream>>>(qkv, h, S);
    else         attn3_k<7><<<B * H, 256, 0, stream>>>(qkv, h, S);
    { dim3 g(D / 128, mb64);
      bgemm_k<2, 768, 64><<<g, 256, 0, stream>>>(h, projT + (size_t)l * D * D, proj_b + (size_t)l * D,
                                                 tb, M, D, nullptr); }
    ln_k<__hip_bfloat16><<<M, 192, 0, stream>>>(tb, h, ln2_g + (size_t)l * D, ln2_b + (size_t)l * D, D, D);
    { dim3 g(FFD / 128, mb128);
      bgemm_k<3, 768, 128><<<g, 256, 0, stream>>>(h, fc1T + (size_t)l * FFD * D, fc1_b + (size_t)l * FFD,
                                                  ff, M, FFD, nullptr); }
    if (S == S1) {
      dim3 g(D / 128, mb128);
      bgemm_k<2, 3072, 128><<<g, 256, 0, stream>>>(ff, fc2T + (size_t)l * D * FFD, fc2_b + (size_t)l * D,
                                                   tb, M, D, nullptr);
    } else {
      dim3 g(D / 128, mb64);
      bgemm_k<2, 3072, 64><<<g, 256, 0, stream>>>(ff, fc2T + (size_t)l * D * FFD, fc2_b + (size_t)l * D,
                                                  tb, M, D, nullptr);
    }
  };

  for (int l = 0; l < PRUNE; ++l) run_block(t, S1, l);

  score_k<<<(B * NPATCH * 64 + 255) / 256, 256, 0, stream>>>(t, scores);
  select_k<<<B, 256, 0, stream>>>(scores, map);
  gather_k<<<B * S2, 192, 0, stream>>>(t, map, t2);

  for (int l = PRUNE; l < LAYERS; ++l) run_block(t2, S2, l);

  ln_k<float><<<B, 192, 0, stream>>>(t2, hf, norm_g, norm_b, (size_t)S2 * D, D);
  { dim3 g((NC + 63) / 64, (B + 63) / 64);
    gemm_k<<<g, 256, 0, stream>>>(hf, head_w, head_b, out, B, NC, D); }
}

// Round 18
// 4812.709 us; speedup vs baseline: 1.0044x; 1.0044x over previous
//
#include <hip/hip_runtime.h>
#include <hip/hip_bf16.h>
#include <cstddef>
#include <cstdint>

namespace {

constexpr int B = 64, CIN = 3, IMG = 224, PS = 16, GRID_ = 14, NPATCH = 196;
constexpr int D = 768, H = 12, HD = 64, FFD = 3072, NC = 1000;
constexpr int S1 = 197, S2 = 99, KEEP = 98, PRUNE = 6, LAYERS = 12;
constexpr float LN_EPS = 1e-6f;

typedef __attribute__((ext_vector_type(8))) short bf16x8;
typedef __attribute__((ext_vector_type(4))) float f32x4;

__device__ inline float wave_red_sum(float v) {
  #pragma unroll
  for (int off = 32; off > 0; off >>= 1) v += __shfl_xor(v, off, 64);
  return v;
}

// async global->LDS DMA, 16B per lane; LDS dest is wave-uniform base + lane*16
__device__ inline void gl16(const __hip_bfloat16* g, __hip_bfloat16* l) {
  __builtin_amdgcn_global_load_lds(
      (const __attribute__((address_space(1))) void*)g,
      (__attribute__((address_space(3))) void*)l,
      16, 0, 0);
}

// ---------------- weight transpose-convert: src f32 [R][C] -> dst bf16 [C][R] ----------------
__global__ __launch_bounds__(256) void tcvt_k(const float* __restrict__ src,
                                              __hip_bfloat16* __restrict__ dst,
                                              int R, int C, size_t lstride) {
  src += (size_t)blockIdx.z * lstride;
  dst += (size_t)blockIdx.z * lstride;
  __shared__ float tile[32][33];
  int c0 = blockIdx.x * 32, r0 = blockIdx.y * 32;
  int tx = threadIdx.x & 31, ty = threadIdx.x >> 5;  // ty 0..7
  #pragma unroll
  for (int i = 0; i < 32; i += 8) {
    int r = r0 + ty + i, c = c0 + tx;
    tile[ty + i][tx] = (r < R && c < C) ? src[(size_t)r * C + c] : 0.f;
  }
  __syncthreads();
  #pragma unroll
  for (int i = 0; i < 32; i += 8) {
    int c = c0 + ty + i, r = r0 + tx;
    if (c < C && r < R) dst[(size_t)c * R + r] = __float2bfloat16(tile[tx][ty + i]);
  }
}

// ---------------- patch extraction -> bf16 patches (B*196, 768), 8 elems/thread ----------------
__global__ void patchify_k(const float* __restrict__ x, __hip_bfloat16* __restrict__ out) {
  size_t idx8 = (size_t)blockIdx.x * blockDim.x + threadIdx.x;
  size_t total8 = (size_t)B * NPATCH * D / 8;
  if (idx8 >= total8) return;
  size_t idx = idx8 * 8;
  int row = (int)(idx / D), k = (int)(idx % D);  // k multiple of 8
  int b = row / NPATCH, n = row % NPATCH;
  int gr = n / GRID_, gc = n % GRID_;
  int c = k >> 8, rr = (k & 255) >> 4, cc = k & 15;  // cc in {0,8}
  const float* src = &x[((size_t)(b * CIN + c) * IMG + (gr * PS + rr)) * IMG + gc * PS + cc];
  float4 v0 = *(const float4*)src;
  float4 v1 = *(const float4*)(src + 4);
  __hip_bfloat16 tmp[8] = {
      __float2bfloat16(v0.x), __float2bfloat16(v0.y), __float2bfloat16(v0.z), __float2bfloat16(v0.w),
      __float2bfloat16(v1.x), __float2bfloat16(v1.y), __float2bfloat16(v1.z), __float2bfloat16(v1.w)};
  *(bf16x8*)&out[idx] = *(bf16x8*)tmp;
}

// ---------------- bf16 MFMA GEMM: BMx128, BK=32, 3-deep counted-vmcnt (R13 structure) ----------------
// BM=128 (LOADS=4/stage, vmcnt 8/4/0) or BM=64 (LOADS=3/stage, vmcnt 6/3/0).
// Compile-time K (KC) + hoisted per-lane global base pointers.
// XOR swizzle: LDS slot(row,chunk)=chunk^((row>>1)&3), both-sides involution.
// MODE 0: bf16 out = acc + bias        (qkv)
// MODE 1: f32 patch-embed scatter      (patch embed)
// MODE 2: f32 out += acc + bias        (residual: proj, fc2)
// MODE 3: bf16 out = gelu(acc + bias)  (fc1)
template <int MODE, int KC, int BM>
__global__ __launch_bounds__(256) void bgemm_k(
    const __hip_bfloat16* __restrict__ A, const __hip_bfloat16* __restrict__ BT,
    const float* __restrict__ bias, void* __restrict__ Cc,
    int M, int N, const float* __restrict__ extra) {
  constexpr int MR = BM / 32;          // per-wave M fragments (4 or 2)
  __shared__ __hip_bfloat16 As[3][BM * 32];
  __shared__ __hip_bfloat16 Bs[3][128 * 32];
  int tid = threadIdx.x, lane = tid & 63, wv = tid >> 6;
  int wr = wv >> 1, wc = wv & 1;
  int m0 = blockIdx.y * BM, n0 = blockIdx.x * 128;
  int fr = lane & 15, fq = lane >> 4;
  int srow = lane >> 2;
  int scd = (lane & 3) ^ ((lane >> 3) & 3);
  int rswz = (fq ^ ((fr >> 1) & 3)) * 8;
  constexpr int NK = KC >> 5;

  // hoisted per-lane global bases (clamp + 64-bit mul once)
  int ar0 = m0 + (BM == 128 ? wv * 32 : wv * 16) + srow;
  int ga0 = (ar0 < M) ? ar0 : (M - 1);
  const __hip_bfloat16* pa0 = A + (size_t)ga0 * KC + scd * 8;
  const __hip_bfloat16* pa1 = pa0;
  if constexpr (BM == 128) {
    int ar1 = ar0 + 16;
    int ga1 = (ar1 < M) ? ar1 : (M - 1);
    pa1 = A + (size_t)ga1 * KC + scd * 8;
  }
  int br0 = n0 + wv * 32 + srow, br1 = br0 + 16;
  int gb0 = (br0 < N) ? br0 : (N - 1), gb1 = (br1 < N) ? br1 : (N - 1);
  const __hip_bfloat16* pb0 = BT + (size_t)gb0 * KC + scd * 8;
  const __hip_bfloat16* pb1 = BT + (size_t)gb1 * KC + scd * 8;

  auto stage = [&](int buf, int kt) {
    int ko = kt << 5;
    if constexpr (BM == 128) {
      gl16(pa0 + ko, &As[buf][(wv * 32) * 32]);
      gl16(pa1 + ko, &As[buf][(wv * 32 + 16) * 32]);
    } else {
      gl16(pa0 + ko, &As[buf][(wv * 16) * 32]);
    }
    gl16(pb0 + ko, &Bs[buf][(wv * 32) * 32]);
    gl16(pb1 + ko, &Bs[buf][(wv * 32 + 16) * 32]);
  };

  f32x4 acc[MR][4] = {};
  stage(0, 0);
  stage(1, 1);                       // NK >= 2 always
  for (int kt = 0; kt < NK; ++kt) {
    int buf = kt % 3;
    if (kt + 2 < NK) {
      stage((kt + 2) % 3, kt + 2);
      if constexpr (BM == 128) asm volatile("s_waitcnt vmcnt(8)" ::: "memory");
      else                     asm volatile("s_waitcnt vmcnt(6)" ::: "memory");
    } else if (kt + 1 < NK) {
      if constexpr (BM == 128) asm volatile("s_waitcnt vmcnt(4)" ::: "memory");
      else                     asm volatile("s_waitcnt vmcnt(3)" ::: "memory");
    } else {
      asm volatile("s_waitcnt vmcnt(0)" ::: "memory");
    }
    asm volatile("s_barrier" ::: "memory");  // all waves' tile-kt DMA visible
    bf16x8 af[MR], bg[4];
    #pragma unroll
    for (int m = 0; m < MR; ++m)
      af[m] = *(const bf16x8*)&As[buf][(wr * (BM / 2) + m * 16 + fr) * 32 + rswz];
    #pragma unroll
    for (int n = 0; n < 4; ++n)
      bg[n] = *(const bf16x8*)&Bs[buf][(wc * 64 + n * 16 + fr) * 32 + rswz];
    #pragma unroll
    for (int m = 0; m < MR; ++m)
      #pragma unroll
      for (int n = 0; n < 4; ++n)
        acc[m][n] = __builtin_amdgcn_mfma_f32_16x16x32_bf16(af[m], bg[n], acc[m][n], 0, 0, 0);
    asm volatile("s_waitcnt lgkmcnt(0)" ::: "memory");  // my LDS reads complete
    asm volatile("s_barrier" ::: "memory");  // all waves done reading buf kt
  }
  #pragma unroll
  for (int m = 0; m < MR; ++m) {
    #pragma unroll
    for (int n = 0; n < 4; ++n) {
      #pragma unroll
      for (int j = 0; j < 4; ++j) {
        int row = m0 + wr * (BM / 2) + m * 16 + fq * 4 + j;
        int col = n0 + wc * 64 + n * 16 + fr;
        if (row >= M || col >= N) continue;
        float v = acc[m][n][j] + bias[col];
        if (MODE == 0) {
          ((__hip_bfloat16*)Cc)[(size_t)row * N + col] = __float2bfloat16(v);
        } else if (MODE == 1) {
          int b = row / NPATCH, nn = row % NPATCH;
          ((float*)Cc)[((size_t)(b * S1 + 1 + nn)) * D + col] = v + extra[(size_t)(1 + nn) * D + col];
        } else if (MODE == 2) {
          ((float*)Cc)[(size_t)row * N + col] += v;
        } else {
          float g = 0.5f * v * (1.0f + erff(v * 0.7071067811865476f));
          ((__hip_bfloat16*)Cc)[(size_t)row * N + col] = __float2bfloat16(g);
        }
      }
    }
  }
}

// ---------------- f32 GEMM (head only): C = A @ B + bias ----------------
__global__ __launch_bounds__(256) void gemm_k(
    const float* __restrict__ A, const float* __restrict__ Bw,
    const float* __restrict__ bias, float* __restrict__ Cc,
    int M, int N, int K) {
  __shared__ float As[64][17];
  __shared__ float Bs[16][64];
  int tid = threadIdx.x;
  int tx = tid & 15, ty = tid >> 4;
  int m0 = blockIdx.y * 64, n0 = blockIdx.x * 64;
  float acc[4][4] = {};
  for (int k0 = 0; k0 < K; k0 += 16) {
    #pragma unroll
    for (int j = 0; j < 4; ++j) {
      int i = tid + 256 * j;
      int r = i >> 4, c = i & 15;
      int gr = m0 + r;
      As[r][c] = (gr < M) ? A[(size_t)gr * K + (k0 + c)] : 0.f;
    }
    #pragma unroll
    for (int j = 0; j < 4; ++j) {
      int i = tid + 256 * j;
      int r = i >> 6, c = i & 63;
      int gc = n0 + c;
      Bs[r][c] = (gc < N) ? Bw[(size_t)(k0 + r) * N + gc] : 0.f;
    }
    __syncthreads();
    #pragma unroll
    for (int kk = 0; kk < 16; ++kk) {
      float a[4], bb[4];
      #pragma unroll
      for (int ii = 0; ii < 4; ++ii) a[ii] = As[ty * 4 + ii][kk];
      #pragma unroll
      for (int jj = 0; jj < 4; ++jj) bb[jj] = Bs[kk][tx * 4 + jj];
      #pragma unroll
      for (int ii = 0; ii < 4; ++ii)
        #pragma unroll
        for (int jj = 0; jj < 4; ++jj) acc[ii][jj] = fmaf(a[ii], bb[jj], acc[ii][jj]);
    }
    __syncthreads();
  }
  #pragma unroll
  for (int ii = 0; ii < 4; ++ii) {
    int row = m0 + ty * 4 + ii;
    if (row >= M) continue;
    #pragma unroll
    for (int jj = 0; jj < 4; ++jj) {
      int col = n0 + tx * 4 + jj;
      if (col >= N) continue;
      Cc[(size_t)row * N + col] = acc[ii][jj] + bias[col];
    }
  }
}

// ---------------- cls token init ----------------
__global__ void cls_init_k(float* __restrict__ t, const float* __restrict__ cls,
                           const float* __restrict__ pos) {
  int idx = blockIdx.x * blockDim.x + threadIdx.x;
  if (idx >= B * D) return;
  int b = idx / D, d = idx % D;
  t[(size_t)b * S1 * D + d] = cls[d] + pos[d];
}

// ---------------- LayerNorm over last dim (768): 192 threads, float4 loads ----------------
template <typename OutT>
__global__ __launch_bounds__(192) void ln_k(const float* __restrict__ in, OutT* __restrict__ out,
                                            const float* __restrict__ g, const float* __restrict__ bta,
                                            size_t istride, size_t ostride) {
  int row = blockIdx.x, tid = threadIdx.x;  // 192 * 4 = 768
  const float4* p = (const float4*)(in + (size_t)row * istride);
  float4 v = p[tid];
  float s = v.x + v.y + v.z + v.w;
  float s2 = v.x * v.x + v.y * v.y + v.z * v.z + v.w * v.w;
  s = wave_red_sum(s);
  s2 = wave_red_sum(s2);
  __shared__ float r1[3], r2[3];
  int lane = tid & 63, w = tid >> 6;
  if (lane == 0) { r1[w] = s; r2[w] = s2; }
  __syncthreads();
  s = r1[0] + r1[1] + r1[2];
  s2 = r2[0] + r2[1] + r2[2];
  float mean = s * (1.0f / 768.0f);
  float var = s2 * (1.0f / 768.0f) - mean * mean;
  float rs = rsqrtf(var + LN_EPS);
  float4 gv = ((const float4*)g)[tid];
  float4 bv = ((const float4*)bta)[tid];
  float o0 = (v.x - mean) * rs * gv.x + bv.x;
  float o1 = (v.y - mean) * rs * gv.y + bv.y;
  float o2 = (v.z - mean) * rs * gv.z + bv.z;
  float o3 = (v.w - mean) * rs * gv.w + bv.w;
  if constexpr (sizeof(OutT) == 2) {
    __hip_bfloat16 hb[4] = {__float2bfloat16(o0), __float2bfloat16(o1),
                            __float2bfloat16(o2), __float2bfloat16(o3)};
    *(uint2*)((__hip_bfloat16*)out + (size_t)row * ostride + tid * 4) = *(uint2*)hb;
  } else {
    ((float4*)((float*)out + (size_t)row * ostride))[tid] = make_float4(o0, o1, o2, o3);
  }
}

// ---------------- MFMA attention: one block (4 waves) per (b,h) ----------------
// PV phase: P-fragments (ap) hoisted out of the dt loop (depend only on kc).
template <int NT16>
__global__ __launch_bounds__(256) void attn3_k(const __hip_bfloat16* __restrict__ qkv,
                                               __hip_bfloat16* __restrict__ o, int S) {
  constexpr int NT32 = (NT16 + 1) / 2;
  constexpr int COLS = NT32 * 32;
  constexpr int STR = COLS + 8;
  __shared__ __hip_bfloat16 VT[64 * STR];      // VT[d][key]
  __shared__ __hip_bfloat16 P[4][16 * STR];    // per-wave P tile [q][key]
  int bh = blockIdx.x;
  int b = bh / H, hh = bh % H;
  int tid = threadIdx.x, lane = tid & 63, wv = tid >> 6;
  int fr = lane & 15, fq = lane >> 4;
  const size_t rs = 3 * D;
  const __hip_bfloat16* qb = qkv + ((size_t)b * S) * rs + hh * HD;
  const __hip_bfloat16* kb = qb + D;
  const __hip_bfloat16* vb = qb + 2 * D;
  // vectorized V staging: one bf16x8 global load per (key, 8-d chunk)
  for (int idx = tid; idx < COLS * 8; idx += 256) {
    int key = idx >> 3, d0 = (idx & 7) * 8;
    bf16x8 v = {};
    if (key < S) v = *(const bf16x8*)(vb + (size_t)key * rs + d0);
    #pragma unroll
    for (int j = 0; j < 8; ++j)
      VT[(d0 + j) * STR + key] = ((const __hip_bfloat16*)&v)[j];
  }
  if (NT16 & 1) {
    const __hip_bfloat16 z = __float2bfloat16(0.f);
    for (int idx = lane; idx < 16 * 16; idx += 64)
      P[wv][(idx >> 4) * STR + NT16 * 16 + (idx & 15)] = z;
  }
  __syncthreads();

  for (int qt = wv; qt * 16 < S; qt += 4) {
    int q0 = qt * 16;
    int qrow = q0 + fr;
    const __hip_bfloat16* qp = qb + (size_t)(qrow < S ? qrow : 0) * rs + fq * 8;
    bf16x8 aq0 = *(const bf16x8*)(qp);
    bf16x8 aq1 = *(const bf16x8*)(qp + 32);
    f32x4 sc[NT16];
    #pragma unroll
    for (int kt = 0; kt < NT16; ++kt) {
      int krow = kt * 16 + fr;
      const __hip_bfloat16* kp = kb + (size_t)(krow < S ? krow : 0) * rs + fq * 8;
      bf16x8 bk0 = *(const bf16x8*)(kp);
      bf16x8 bk1 = *(const bf16x8*)(kp + 32);
      f32x4 a = {};
      a = __builtin_amdgcn_mfma_f32_16x16x32_bf16(aq0, bk0, a, 0, 0, 0);
      a = __builtin_amdgcn_mfma_f32_16x16x32_bf16(aq1, bk1, a, 0, 0, 0);
      sc[kt] = a;
    }
    float lj[4];
    #pragma unroll
    for (int jj = 0; jj < 4; ++jj) {
      float mx = -1e30f;
      #pragma unroll
      for (int kt = 0; kt < NT16; ++kt) {
        float v = sc[kt][jj] * 0.125f;
        if (kt * 16 + fr >= S) v = -1e30f;
        sc[kt][jj] = v;
        mx = fmaxf(mx, v);
      }
      mx = fmaxf(mx, __shfl_xor(mx, 1, 64));
      mx = fmaxf(mx, __shfl_xor(mx, 2, 64));
      mx = fmaxf(mx, __shfl_xor(mx, 4, 64));
      mx = fmaxf(mx, __shfl_xor(mx, 8, 64));
      float sum = 0.f;
      #pragma unroll
      for (int kt = 0; kt < NT16; ++kt) {
        float p = __expf(sc[kt][jj] - mx);
        sc[kt][jj] = p;
        sum += p;
      }
      sum += __shfl_xor(sum, 1, 64);
      sum += __shfl_xor(sum, 2, 64);
      sum += __shfl_xor(sum, 4, 64);
      sum += __shfl_xor(sum, 8, 64);
      lj[jj] = 1.0f / sum;
    }
    __hip_bfloat16* pw = &P[wv][0];
    #pragma unroll
    for (int kt = 0; kt < NT16; ++kt)
      #pragma unroll
      for (int jj = 0; jj < 4; ++jj)
        pw[(fq * 4 + jj) * STR + kt * 16 + fr] = __float2bfloat16(sc[kt][jj]);
    // hoisted P fragments: depend only on kc, not dt
    bf16x8 ap[NT32];
    #pragma unroll
    for (int kc = 0; kc < NT32; ++kc)
      ap[kc] = *(const bf16x8*)&pw[fr * STR + kc * 32 + fq * 8];
    #pragma unroll
    for (int dt = 0; dt < 4; ++dt) {
      f32x4 oa = {};
      #pragma unroll
      for (int kc = 0; kc < NT32; ++kc) {
        bf16x8 bv = *(const bf16x8*)&VT[(dt * 16 + fr) * STR + kc * 32 + fq * 8];
        oa = __builtin_amdgcn_mfma_f32_16x16x32_bf16(ap[kc], bv, oa, 0, 0, 0);
      }
      #pragma unroll
      for (int jj = 0; jj < 4; ++jj) {
        int orow = q0 + fq * 4 + jj;
        if (orow < S)
          o[((size_t)(b * S + orow)) * D + hh * HD + dt * 16 + fr] =
              __float2bfloat16(oa[jj] * lj[jj]);
      }
    }
  }
}

// ---------------- token scores: float4 loads ----------------
__global__ void score_k(const float* __restrict__ t, float* __restrict__ scores) {
  int gw = (blockIdx.x * blockDim.x + threadIdx.x) >> 6;
  int lane = threadIdx.x & 63;
  if (gw >= B * NPATCH) return;
  int b = gw / NPATCH, n = gw % NPATCH;
  const float4* p = (const float4*)(t + ((size_t)(b * S1) + 1 + n) * D);
  float a = 0.f;
  #pragma unroll
  for (int j = lane; j < D / 4; j += 64) {
    float4 v = p[j];
    a += v.x * v.x + v.y * v.y + v.z * v.z + v.w * v.w;
  }
  a = wave_red_sum(a);
  if (lane == 0) scores[gw] = sqrtf(a);
}

// ---------------- top-98 selection (exact jax.lax.top_k tie-break) ----------------
__global__ __launch_bounds__(256) void select_k(const float* __restrict__ scores, int* __restrict__ map) {
  int b = blockIdx.x;
  __shared__ float s[NPATCH];
  __shared__ int flag[NPATCH];
  int i = threadIdx.x;
  if (i < NPATCH) s[i] = scores[b * NPATCH + i];
  __syncthreads();
  if (i < NPATCH) {
    float si = s[i];
    int r = 0;
    for (int j = 0; j < NPATCH; ++j) {
      float sj = s[j];
      r += (sj > si) || (sj == si && j < i);
    }
    flag[i] = (r < KEEP) ? 1 : 0;
  }
  __syncthreads();
  if (i < NPATCH && flag[i]) {
    int p = 0;
    for (int j = 0; j < i; ++j) p += flag[j];
    map[b * (KEEP + 1) + 1 + p] = 1 + i;
  }
  if (i == 0) map[b * (KEEP + 1)] = 0;
}

// ---------------- gather selected rows: float4 copies ----------------
__global__ void gather_k(const float* __restrict__ t, const int* __restrict__ map,
                         float* __restrict__ t2) {
  int br = blockIdx.x;
  int b = br / S2;
  int src = map[br];
  const float4* p = (const float4*)(t + ((size_t)b * S1 + src) * D);
  float4* q = (float4*)(t2 + (size_t)br * D);
  for (int j = threadIdx.x; j < D / 4; j += blockDim.x) q[j] = p[j];
}

}  // namespace

extern "C" void kernel_launch(void* const* d_in, const int* in_sizes, int n_in,
                              void* d_out, int out_size, void* d_ws, size_t ws_size,
                              hipStream_t stream) {
  const float* x       = (const float*)d_in[0];
  const float* patch_w = (const float*)d_in[1];
  const float* patch_b = (const float*)d_in[2];
  const float* cls_tok = (const float*)d_in[3];
  const float* pos_emb = (const float*)d_in[4];
  const float* ln1_g   = (const float*)d_in[5];
  const float* ln1_b   = (const float*)d_in[6];
  const float* qkv_w   = (const float*)d_in[7];
  const float* qkv_b   = (const float*)d_in[8];
  const float* proj_w  = (const float*)d_in[9];
  const float* proj_b  = (const float*)d_in[10];
  const float* ln2_g   = (const float*)d_in[11];
  const float* ln2_b   = (const float*)d_in[12];
  const float* fc1_w   = (const float*)d_in[13];
  const float* fc1_b   = (const float*)d_in[14];
  const float* fc2_w   = (const float*)d_in[15];
  const float* fc2_b   = (const float*)d_in[16];
  const float* norm_g  = (const float*)d_in[17];
  const float* norm_b  = (const float*)d_in[18];
  const float* head_w  = (const float*)d_in[19];
  const float* head_b  = (const float*)d_in[20];
  float* out = (float*)d_out;

  // ---- workspace layout (256B-aligned regions) ----
  char* wp = (char*)d_ws;
  auto alloc = [&](size_t bytes) { char* r = wp; wp += (bytes + 255) & ~(size_t)255; return r; };
  float* t   = (float*)alloc((size_t)B * S1 * D * 4);
  float* t2  = (float*)alloc((size_t)B * S2 * D * 4);
  float* hf  = (float*)alloc((size_t)B * D * 4);
  float* scores = (float*)alloc((size_t)B * NPATCH * 4);
  int*   map    = (int*)alloc((size_t)B * S2 * 4);
  __hip_bfloat16* h   = (__hip_bfloat16*)alloc((size_t)B * S1 * D * 2);
  __hip_bfloat16* qkv = (__hip_bfloat16*)alloc((size_t)B * S1 * 3 * D * 2);
  __hip_bfloat16* ff  = (__hip_bfloat16*)alloc((size_t)B * S1 * FFD * 2);
  __hip_bfloat16* qkvT  = (__hip_bfloat16*)alloc((size_t)LAYERS * 3 * D * D * 2);
  __hip_bfloat16* projT = (__hip_bfloat16*)alloc((size_t)LAYERS * D * D * 2);
  __hip_bfloat16* fc1T  = (__hip_bfloat16*)alloc((size_t)LAYERS * FFD * D * 2);
  __hip_bfloat16* fc2T  = (__hip_bfloat16*)alloc((size_t)LAYERS * D * FFD * 2);
  __hip_bfloat16* patchT = (__hip_bfloat16*)alloc((size_t)D * D * 2);
  __hip_bfloat16* patches = ff;  // alias: ff unused during patch embed

  // ---- weight transpose-convert ----
  { dim3 g(3 * D / 32, D / 32, LAYERS);
    tcvt_k<<<g, 256, 0, stream>>>(qkv_w, qkvT, D, 3 * D, (size_t)D * 3 * D); }
  { dim3 g(D / 32, D / 32, LAYERS);
    tcvt_k<<<g, 256, 0, stream>>>(proj_w, projT, D, D, (size_t)D * D); }
  { dim3 g(FFD / 32, D / 32, LAYERS);
    tcvt_k<<<g, 256, 0, stream>>>(fc1_w, fc1T, D, FFD, (size_t)D * FFD); }
  { dim3 g(D / 32, FFD / 32, LAYERS);
    tcvt_k<<<g, 256, 0, stream>>>(fc2_w, fc2T, FFD, D, (size_t)FFD * D); }
  { dim3 g(D / 32, D / 32, 1);
    tcvt_k<<<g, 256, 0, stream>>>(patch_w, patchT, D, D, 0); }

  // ---- patch embedding (+cls, +pos) ----
  {
    size_t total8 = (size_t)B * NPATCH * D / 8;
    patchify_k<<<(unsigned)((total8 + 255) / 256), 256, 0, stream>>>(x, patches);
    dim3 g(D / 128, (B * NPATCH) / 128);
    bgemm_k<1, 768, 128><<<g, 256, 0, stream>>>(patches, patchT, patch_b, t, B * NPATCH, D, pos_emb);
    cls_init_k<<<(B * D + 255) / 256, 256, 0, stream>>>(t, cls_tok, pos_emb);
  }

  auto run_block = [&](float* tb, int S, int l) {
    int M = B * S;
    int mb128 = (M + 127) / 128;
    int mb64 = (M + 63) / 64;
    ln_k<__hip_bfloat16><<<M, 192, 0, stream>>>(tb, h, ln1_g + (size_t)l * D, ln1_b + (size_t)l * D, D, D);
    { dim3 g(3 * D / 128, mb128);
      bgemm_k<0, 768, 128><<<g, 256, 0, stream>>>(h, qkvT + (size_t)l * 3 * D * D, qkv_b + (size_t)l * 3 * D,
                                                  qkv, M, 3 * D, nullptr); }
    if (S == S1) attn3_k<13><<<B * H, 256, 0, stream>>>(qkv, h, S);
    else         attn3_k<7><<<B * H, 256, 0, stream>>>(qkv, h, S);
    // proj: BM=128 for S1 (residency not binding, better per-block efficiency);
    //       BM=64 for S2 (300 blocks at BM=128 would starve CUs)
    if (S == S1) {
      dim3 g(D / 128, mb128);
      bgemm_k<2, 768, 128><<<g, 256, 0, stream>>>(h, projT + (size_t)l * D * D, proj_b + (size_t)l * D,
                                                  tb, M, D, nullptr);
    } else {
      dim3 g(D / 128, mb64);
      bgemm_k<2, 768, 64><<<g, 256, 0, stream>>>(h, projT + (size_t)l * D * D, proj_b + (size_t)l * D,
                                                 tb, M, D, nullptr);
    }
    ln_k<__hip_bfloat16><<<M, 192, 0, stream>>>(tb, h, ln2_g + (size_t)l * D, ln2_b + (size_t)l * D, D, D);
    { dim3 g(FFD / 128, mb128);
      bgemm_k<3, 768, 128><<<g, 256, 0, stream>>>(h, fc1T + (size_t)l * FFD * D, fc1_b + (size_t)l * FFD,
                                                  ff, M, FFD, nullptr); }
    if (S == S1) {
      dim3 g(D / 128, mb128);
      bgemm_k<2, 3072, 128><<<g, 256, 0, stream>>>(ff, fc2T + (size_t)l * D * FFD, fc2_b + (size_t)l * D,
                                                   tb, M, D, nullptr);
    } else {
      dim3 g(D / 128, mb64);
      bgemm_k<2, 3072, 64><<<g, 256, 0, stream>>>(ff, fc2T + (size_t)l * D * FFD, fc2_b + (size_t)l * D,
                                                  tb, M, D, nullptr);
    }
  };

  for (int l = 0; l < PRUNE; ++l) run_block(t, S1, l);

  score_k<<<(B * NPATCH * 64 + 255) / 256, 256, 0, stream>>>(t, scores);
  select_k<<<B, 256, 0, stream>>>(scores, map);
  gather_k<<<B * S2, 192, 0, stream>>>(t, map, t2);

  for (int l = PRUNE; l < LAYERS; ++l) run_block(t2, S2, l);

  ln_k<float><<<B, 192, 0, stream>>>(t2, hf, norm_g, norm_b, (size_t)S2 * D, D);
  { dim3 g((NC + 63) / 64, (B + 63) / 64);
    gemm_k<<<g, 256, 0, stream>>>(hf, head_w, head_b, out, B, NC, D); }
}